// Round 1
// baseline (2495.770 us; speedup 1.0000x reference)
//
#include <hip/hip_runtime.h>
#include <hip/hip_bf16.h>
#include <math.h>

#define IN_DIM 128
#define LAT 32
#define HID 128

// ---------------- kernels ----------------

__global__ void compute_idx_kernel(const int* __restrict__ batch, int* __restrict__ idx,
                                   int N, int G) {
    int g = blockIdx.x * blockDim.x + threadIdx.x;
    if (g >= G) return;
    // lower_bound: first i with batch[i] >= g
    int lo = 0, hi = N;
    while (lo < hi) {
        int mid = (lo + hi) >> 1;
        if (batch[mid] < g) lo = mid + 1; else hi = mid;
    }
    idx[g] = lo;
}

__global__ void deg_kernel(const int* __restrict__ ei, int* __restrict__ degI, long long E) {
    long long tid = (long long)blockIdx.x * blockDim.x + threadIdx.x;
    long long stride = (long long)gridDim.x * blockDim.x;
    for (long long e = tid; e < E; e += stride) {
        int d = ei[E + e];
        atomicAdd(&degI[d], 1);
    }
}

__global__ void dinv_kernel(const int* __restrict__ degI, float* __restrict__ dinv, int N) {
    int v = blockIdx.x * blockDim.x + threadIdx.x;
    if (v >= N) return;
    // +1 for self-loop; deg >= 1 always
    dinv[v] = rsqrtf((float)(degI[v] + 1));
}

// t[N,32] = x[N,128] @ W[128,32]
__global__ void gemm_in_kernel(const float* __restrict__ x, const float* __restrict__ W,
                               float* __restrict__ t, int N) {
    __shared__ float Wl[IN_DIM * LAT];
    for (int i = threadIdx.x; i < IN_DIM * LAT; i += blockDim.x) Wl[i] = W[i];
    __syncthreads();
    int rows_per_block = blockDim.x / LAT;  // 8
    int r = blockIdx.x * rows_per_block + (int)(threadIdx.x / LAT);
    int c = threadIdx.x & (LAT - 1);
    if (r >= N) return;
    const float* xr = x + (long long)r * IN_DIM;
    float acc = 0.f;
#pragma unroll 8
    for (int k = 0; k < IN_DIM; k++) acc += xr[k] * Wl[k * LAT + c];
    t[(long long)r * LAT + c] = acc;
}

// t[N,32] = h[N,32] @ W[32,32]
__global__ void gemm_lat_kernel(const float* __restrict__ h, const float* __restrict__ W,
                                float* __restrict__ t, int N) {
    __shared__ float Wl[LAT * LAT];
    for (int i = threadIdx.x; i < LAT * LAT; i += blockDim.x) Wl[i] = W[i];
    __syncthreads();
    long long idx = (long long)blockIdx.x * blockDim.x + threadIdx.x;
    long long total = (long long)N * LAT;
    if (idx >= total) return;
    int v = (int)(idx >> 5);
    int c = (int)(idx & 31);
    const float* hr = h + (long long)v * LAT;
    float acc = 0.f;
#pragma unroll
    for (int k = 0; k < LAT; k++) acc += hr[k] * Wl[k * LAT + c];
    t[idx] = acc;
}

// agg[dst,f] += t[src,f] * dinv[src]*dinv[dst]  for every edge
__global__ void scatter_kernel(const int* __restrict__ ei, const float* __restrict__ dinv,
                               const float* __restrict__ t, float* __restrict__ agg,
                               long long E) {
    long long total = E * LAT;
    long long tid = (long long)blockIdx.x * blockDim.x + threadIdx.x;
    long long stride = (long long)gridDim.x * blockDim.x;
    for (long long p = tid; p < total; p += stride) {
        long long e = p >> 5;
        int f = (int)(p & 31);
        int s = ei[e];
        int d = ei[E + e];
        float nrm = dinv[s] * dinv[d];
        atomicAdd(&agg[(long long)d * LAT + f], t[(long long)s * LAT + f] * nrm);
    }
}

// h_out (in t buffer) = tanh(agg + t*dinv^2 + b)
__global__ void tanh_kernel(const float* __restrict__ agg, float* __restrict__ t_h,
                            const float* __restrict__ dinv, const float* __restrict__ b,
                            int N) {
    long long idx = (long long)blockIdx.x * blockDim.x + threadIdx.x;
    long long total = (long long)N * LAT;
    if (idx >= total) return;
    int v = (int)(idx >> 5);
    int f = (int)(idx & 31);
    float s = dinv[v];
    float val = agg[idx] + t_h[idx] * s * s + b[f];
    t_h[idx] = tanhf(val);
}

__global__ void extract_pooled_kernel(const float* __restrict__ h, const int* __restrict__ idx,
                                      float* __restrict__ pooled, int G, int col_off) {
    int tid = blockIdx.x * blockDim.x + threadIdx.x;
    if (tid >= G * LAT) return;
    int g = tid >> 5;
    int f = tid & 31;
    pooled[(long long)g * (3 * LAT) + col_off + f] = h[(long long)idx[g] * LAT + f];
}

// per-graph MLP head: relu(pooled@Wl1+bl1) @ Wl2 + bl2 -> log_softmax
__global__ void mlp_head_kernel(const float* __restrict__ pooled,
                                const float* __restrict__ Wl1, const float* __restrict__ bl1,
                                const float* __restrict__ Wl2, const float* __restrict__ bl2,
                                float* __restrict__ out, int G) {
    __shared__ float prow[3 * LAT];
    __shared__ float red0[HID];
    __shared__ float red1[HID];
    int g = blockIdx.x;
    int j = threadIdx.x;  // 0..127
    if (j < 3 * LAT) prow[j] = pooled[(long long)g * (3 * LAT) + j];
    __syncthreads();
    float acc = bl1[j];
#pragma unroll 8
    for (int k = 0; k < 3 * LAT; k++) acc += prow[k] * Wl1[k * HID + j];
    float hj = fmaxf(acc, 0.f);
    red0[j] = hj * Wl2[j * 2 + 0];
    red1[j] = hj * Wl2[j * 2 + 1];
    __syncthreads();
    for (int s = HID / 2; s > 0; s >>= 1) {
        if (j < s) { red0[j] += red0[j + s]; red1[j] += red1[j + s]; }
        __syncthreads();
    }
    if (j == 0) {
        float l0 = red0[0] + bl2[0];
        float l1 = red1[0] + bl2[1];
        float m = fmaxf(l0, l1);
        float lse = m + logf(expf(l0 - m) + expf(l1 - m));
        out[(long long)g * 2 + 0] = l0 - lse;
        out[(long long)g * 2 + 1] = l1 - lse;
    }
}

// ---------------- launch ----------------

extern "C" void kernel_launch(void* const* d_in, const int* in_sizes, int n_in,
                              void* d_out, int out_size, void* d_ws, size_t ws_size,
                              hipStream_t stream) {
    const float* x    = (const float*)d_in[0];
    const int*   ei   = (const int*)d_in[1];
    const int*   batch= (const int*)d_in[2];
    const float* W1   = (const float*)d_in[3];
    const float* b1   = (const float*)d_in[4];
    const float* W2   = (const float*)d_in[5];
    const float* b2   = (const float*)d_in[6];
    const float* W3   = (const float*)d_in[7];
    const float* b3   = (const float*)d_in[8];
    const float* Wl1  = (const float*)d_in[9];
    const float* bl1  = (const float*)d_in[10];
    const float* Wl2  = (const float*)d_in[11];
    const float* bl2  = (const float*)d_in[12];
    float* out = (float*)d_out;

    const int N = in_sizes[2];
    const long long E = (long long)in_sizes[1] / 2;
    const int G = out_size / 2;

    // workspace layout (bytes)
    char* ws = (char*)d_ws;
    float* bufA   = (float*)ws;                               // N*32 f32
    float* bufB   = (float*)(ws + (size_t)N * LAT * 4);       // N*32 f32
    float* dinv   = (float*)(ws + (size_t)N * LAT * 8);       // N f32
    int*   degI   = (int*)  (ws + (size_t)N * LAT * 8 + (size_t)N * 4);   // N i32
    int*   idx    = (int*)  (ws + (size_t)N * LAT * 8 + (size_t)N * 8);   // G i32
    float* pooled = (float*)(ws + (size_t)N * LAT * 8 + (size_t)N * 8 + (size_t)G * 4); // G*96 f32

    const int BS = 256;
    const int nvBlocks = (N * LAT + BS - 1) / BS;       // for N*32-sized kernels
    const int rowBlocks = (N + 7) / 8;                  // gemm_in: 8 rows/block
    const int gsBlocks = 2048;                          // grid-stride kernels

    // degree + dinv + readout indices
    hipMemsetAsync(degI, 0, (size_t)N * 4, stream);
    compute_idx_kernel<<<(G + BS - 1) / BS, BS, 0, stream>>>(batch, idx, N, G);
    deg_kernel<<<gsBlocks, BS, 0, stream>>>(ei, degI, E);
    dinv_kernel<<<(N + BS - 1) / BS, BS, 0, stream>>>(degI, dinv, N);

    // ---- layer 1: t1 = x@W1 (bufA); agg1 (bufB); h1 (bufA) ----
    gemm_in_kernel<<<rowBlocks, BS, 0, stream>>>(x, W1, bufA, N);
    hipMemsetAsync(bufB, 0, (size_t)N * LAT * 4, stream);
    scatter_kernel<<<gsBlocks, BS, 0, stream>>>(ei, dinv, bufA, bufB, E);
    tanh_kernel<<<nvBlocks, BS, 0, stream>>>(bufB, bufA, dinv, b1, N);
    extract_pooled_kernel<<<(G * LAT + BS - 1) / BS, BS, 0, stream>>>(bufA, idx, pooled, G, 0);

    // ---- layer 2: t2 = h1@W2 (bufB); agg2 (bufA); h2 (bufB) ----
    gemm_lat_kernel<<<nvBlocks, BS, 0, stream>>>(bufA, W2, bufB, N);
    hipMemsetAsync(bufA, 0, (size_t)N * LAT * 4, stream);
    scatter_kernel<<<gsBlocks, BS, 0, stream>>>(ei, dinv, bufB, bufA, E);
    tanh_kernel<<<nvBlocks, BS, 0, stream>>>(bufA, bufB, dinv, b2, N);
    extract_pooled_kernel<<<(G * LAT + BS - 1) / BS, BS, 0, stream>>>(bufB, idx, pooled, G, LAT);

    // ---- layer 3: t3 = h2@W3 (bufA); agg3 (bufB); h3 (bufA) ----
    gemm_lat_kernel<<<nvBlocks, BS, 0, stream>>>(bufB, W3, bufA, N);
    hipMemsetAsync(bufB, 0, (size_t)N * LAT * 4, stream);
    scatter_kernel<<<gsBlocks, BS, 0, stream>>>(ei, dinv, bufA, bufB, E);
    tanh_kernel<<<nvBlocks, BS, 0, stream>>>(bufB, bufA, dinv, b3, N);
    extract_pooled_kernel<<<(G * LAT + BS - 1) / BS, BS, 0, stream>>>(bufA, idx, pooled, G, 2 * LAT);

    // ---- MLP head ----
    mlp_head_kernel<<<G, HID, 0, stream>>>(pooled, Wl1, bl1, Wl2, bl2, out, G);
}

// Round 2
// 1671.998 us; speedup vs baseline: 1.4927x; 1.4927x over previous
//
#include <hip/hip_runtime.h>
#include <hip/hip_bf16.h>
#include <math.h>

#define IN_DIM 128
#define LAT 32
#define HID 128
#define SCAN_CHUNK 1024   // elements per scan block (256 threads x 4)

// ---------------- small setup kernels ----------------

__global__ void compute_idx_kernel(const int* __restrict__ batch, int* __restrict__ idx,
                                   int N, int G) {
    int g = blockIdx.x * blockDim.x + threadIdx.x;
    if (g >= G) return;
    int lo = 0, hi = N;
    while (lo < hi) {
        int mid = (lo + hi) >> 1;
        if (batch[mid] < g) lo = mid + 1; else hi = mid;
    }
    idx[g] = lo;
}

__global__ void deg_kernel(const int* __restrict__ ei, int* __restrict__ degI, long long E) {
    long long tid = (long long)blockIdx.x * blockDim.x + threadIdx.x;
    long long stride = (long long)gridDim.x * blockDim.x;
    for (long long e = tid; e < E; e += stride) {
        atomicAdd(&degI[ei[E + e]], 1);
    }
}

__global__ void dinv_kernel(const int* __restrict__ degI, float* __restrict__ dinv, int N) {
    int v = blockIdx.x * blockDim.x + threadIdx.x;
    if (v >= N) return;
    dinv[v] = rsqrtf((float)(degI[v] + 1));  // +1 self-loop
}

// ---------------- exclusive scan (rowptr) ----------------

__global__ void scan1_kernel(const int* __restrict__ deg, int* __restrict__ chunkSums, int N) {
    __shared__ int s[256];
    int base = blockIdx.x * SCAN_CHUNK + threadIdx.x * 4;
    int sum = 0;
#pragma unroll
    for (int k = 0; k < 4; k++) {
        int i = base + k;
        sum += (i < N) ? deg[i] : 0;
    }
    s[threadIdx.x] = sum;
    __syncthreads();
    for (int off = 128; off > 0; off >>= 1) {
        if (threadIdx.x < off) s[threadIdx.x] += s[threadIdx.x + off];
        __syncthreads();
    }
    if (threadIdx.x == 0) chunkSums[blockIdx.x] = s[0];
}

__global__ void scan2_kernel(const int* __restrict__ chunkSums, int* __restrict__ chunkOff,
                             int* __restrict__ rowptr, int C, int N, int Etot) {
    __shared__ int s[256];
    int t = threadIdx.x;
    s[t] = (t < C) ? chunkSums[t] : 0;
    __syncthreads();
    for (int off = 1; off < 256; off <<= 1) {
        int v = (t >= off) ? s[t - off] : 0;
        __syncthreads();
        s[t] += v;
        __syncthreads();
    }
    if (t < C) chunkOff[t] = (t > 0) ? s[t - 1] : 0;
    if (t == 0) rowptr[N] = Etot;
}

__global__ void scan3_kernel(const int* __restrict__ deg, const int* __restrict__ chunkOff,
                             int* __restrict__ rowptr, int* __restrict__ cursor, int N) {
    __shared__ int s[256];
    int t = threadIdx.x;
    int base = blockIdx.x * SCAN_CHUNK + t * 4;
    int vals[4];
    int sum = 0;
#pragma unroll
    for (int k = 0; k < 4; k++) {
        int i = base + k;
        int v = (i < N) ? deg[i] : 0;
        vals[k] = sum;          // exclusive within thread
        sum += v;
    }
    s[t] = sum;
    __syncthreads();
    for (int off = 1; off < 256; off <<= 1) {
        int v = (t >= off) ? s[t - off] : 0;
        __syncthreads();
        s[t] += v;
        __syncthreads();
    }
    int thrOff = ((t > 0) ? s[t - 1] : 0) + chunkOff[blockIdx.x];
#pragma unroll
    for (int k = 0; k < 4; k++) {
        int i = base + k;
        if (i < N) {
            int r = thrOff + vals[k];
            rowptr[i] = r;
            cursor[i] = r;
        }
    }
}

__global__ void fill_csr_kernel(const int* __restrict__ ei, int* __restrict__ cursor,
                                int* __restrict__ csr_src, long long E) {
    long long tid = (long long)blockIdx.x * blockDim.x + threadIdx.x;
    long long stride = (long long)gridDim.x * blockDim.x;
    for (long long e = tid; e < E; e += stride) {
        int d = ei[E + e];
        int slot = atomicAdd(&cursor[d], 1);
        csr_src[slot] = ei[e];
    }
}

// ---------------- transforms (GEMM with dinv-scaled epilogue) ----------------

// tp[N,32] = (x[N,128] @ W[128,32]) * dinv[v]
__global__ void gemm_in_kernel(const float* __restrict__ x, const float* __restrict__ W,
                               const float* __restrict__ dinv, float* __restrict__ tp, int N) {
    __shared__ float Wl[IN_DIM * LAT];
    for (int i = threadIdx.x; i < IN_DIM * LAT; i += blockDim.x) Wl[i] = W[i];
    __syncthreads();
    int r = blockIdx.x * 8 + (int)(threadIdx.x >> 5);
    int c = threadIdx.x & 31;
    if (r >= N) return;
    const float* xr = x + (long long)r * IN_DIM;
    float acc = 0.f;
#pragma unroll 8
    for (int k = 0; k < IN_DIM; k++) acc += xr[k] * Wl[k * LAT + c];
    tp[(long long)r * LAT + c] = acc * dinv[r];
}

// tp[N,32] = (h[N,32] @ W[32,32]) * dinv[v]
__global__ void gemm_lat_kernel(const float* __restrict__ h, const float* __restrict__ W,
                                const float* __restrict__ dinv, float* __restrict__ tp, int N) {
    __shared__ float Wl[LAT * LAT];
    for (int i = threadIdx.x; i < LAT * LAT; i += blockDim.x) Wl[i] = W[i];
    __syncthreads();
    long long idx = (long long)blockIdx.x * blockDim.x + threadIdx.x;
    long long total = (long long)N * LAT;
    if (idx >= total) return;
    int v = (int)(idx >> 5);
    int c = (int)(idx & 31);
    const float* hr = h + (long long)v * LAT;
    float acc = 0.f;
#pragma unroll
    for (int k = 0; k < LAT; k++) acc += hr[k] * Wl[k * LAT + c];
    tp[idx] = acc * dinv[v];
}

// ---------------- gather-reduce aggregation + tanh ----------------
// h[v,f] = tanh( dinv[v] * ( sum_{s in nbr(v)} tp[s,f] + tp[v,f] ) + b[f] )
__global__ void gather_tanh_kernel(const int* __restrict__ rowptr, const int* __restrict__ csr_src,
                                   const float* __restrict__ tp, const float* __restrict__ dinv,
                                   const float* __restrict__ b, float* __restrict__ h, int N) {
    int v = blockIdx.x * 8 + (int)(threadIdx.x >> 5);
    int f = threadIdx.x & 31;
    if (v >= N) return;
    int start = rowptr[v];
    int end = rowptr[v + 1];
    float acc = tp[(long long)v * LAT + f];   // self-loop term
    for (int base = start; base < end; base += 32) {
        int e = base + f;
        int s = (e < end) ? csr_src[e] : 0;   // coalesced index load
        int cnt = min(32, end - base);
        for (int j = 0; j < cnt; j++) {
            int sj = __shfl(s, j, 32);        // broadcast within half-wave
            acc += tp[(long long)sj * LAT + f];  // coalesced 128B row
        }
    }
    h[(long long)v * LAT + f] = tanhf(dinv[v] * acc + b[f]);
}

__global__ void extract_pooled_kernel(const float* __restrict__ h, const int* __restrict__ idx,
                                      float* __restrict__ pooled, int G, int col_off) {
    int tid = blockIdx.x * blockDim.x + threadIdx.x;
    if (tid >= G * LAT) return;
    int g = tid >> 5;
    int f = tid & 31;
    pooled[(long long)g * (3 * LAT) + col_off + f] = h[(long long)idx[g] * LAT + f];
}

// ---------------- MLP head ----------------

__global__ void mlp_head_kernel(const float* __restrict__ pooled,
                                const float* __restrict__ Wl1, const float* __restrict__ bl1,
                                const float* __restrict__ Wl2, const float* __restrict__ bl2,
                                float* __restrict__ out, int G) {
    __shared__ float prow[3 * LAT];
    __shared__ float red0[HID];
    __shared__ float red1[HID];
    int g = blockIdx.x;
    int j = threadIdx.x;
    if (j < 3 * LAT) prow[j] = pooled[(long long)g * (3 * LAT) + j];
    __syncthreads();
    float acc = bl1[j];
#pragma unroll 8
    for (int k = 0; k < 3 * LAT; k++) acc += prow[k] * Wl1[k * HID + j];
    float hj = fmaxf(acc, 0.f);
    red0[j] = hj * Wl2[j * 2 + 0];
    red1[j] = hj * Wl2[j * 2 + 1];
    __syncthreads();
    for (int s = HID / 2; s > 0; s >>= 1) {
        if (j < s) { red0[j] += red0[j + s]; red1[j] += red1[j + s]; }
        __syncthreads();
    }
    if (j == 0) {
        float l0 = red0[0] + bl2[0];
        float l1 = red1[0] + bl2[1];
        float m = fmaxf(l0, l1);
        float lse = m + logf(expf(l0 - m) + expf(l1 - m));
        out[(long long)g * 2 + 0] = l0 - lse;
        out[(long long)g * 2 + 1] = l1 - lse;
    }
}

// ---------------- launch ----------------

extern "C" void kernel_launch(void* const* d_in, const int* in_sizes, int n_in,
                              void* d_out, int out_size, void* d_ws, size_t ws_size,
                              hipStream_t stream) {
    const float* x    = (const float*)d_in[0];
    const int*   ei   = (const int*)d_in[1];
    const int*   batch= (const int*)d_in[2];
    const float* W1   = (const float*)d_in[3];
    const float* b1   = (const float*)d_in[4];
    const float* W2   = (const float*)d_in[5];
    const float* b2   = (const float*)d_in[6];
    const float* W3   = (const float*)d_in[7];
    const float* b3   = (const float*)d_in[8];
    const float* Wl1  = (const float*)d_in[9];
    const float* bl1  = (const float*)d_in[10];
    const float* Wl2  = (const float*)d_in[11];
    const float* bl2  = (const float*)d_in[12];
    float* out = (float*)d_out;

    const int N = in_sizes[2];
    const long long E = (long long)in_sizes[1] / 2;
    const int G = out_size / 2;
    const int C = (N + SCAN_CHUNK - 1) / SCAN_CHUNK;   // scan chunks (196)

    // workspace layout
    char* ws = (char*)d_ws;
    size_t off = 0;
    float* bufA    = (float*)(ws + off); off += (size_t)N * LAT * 4;
    float* bufB    = (float*)(ws + off); off += (size_t)N * LAT * 4;
    int*   csr_src = (int*)  (ws + off); off += (size_t)E * 4;
    float* dinv    = (float*)(ws + off); off += (size_t)N * 4;
    int*   degI    = (int*)  (ws + off); off += (size_t)N * 4;
    int*   rowptr  = (int*)  (ws + off); off += (size_t)(N + 1) * 4;
    int*   cursor  = (int*)  (ws + off); off += (size_t)N * 4;
    int*   idx     = (int*)  (ws + off); off += (size_t)G * 4;
    float* pooled  = (float*)(ws + off); off += (size_t)G * (3 * LAT) * 4;
    int*   chunkS  = (int*)  (ws + off); off += 256 * 4;
    int*   chunkO  = (int*)  (ws + off); off += 256 * 4;

    const int BS = 256;
    const int nvBlocks = (N * LAT + BS - 1) / BS;
    const int rowBlocks = (N + 7) / 8;   // 8 nodes/block for gemm_in & gather
    const int gsBlocks = 2048;

    // ---- graph preprocessing: degrees, dinv, readout idx, CSR ----
    hipMemsetAsync(degI, 0, (size_t)N * 4, stream);
    compute_idx_kernel<<<(G + BS - 1) / BS, BS, 0, stream>>>(batch, idx, N, G);
    deg_kernel<<<gsBlocks, BS, 0, stream>>>(ei, degI, E);
    dinv_kernel<<<(N + BS - 1) / BS, BS, 0, stream>>>(degI, dinv, N);
    scan1_kernel<<<C, BS, 0, stream>>>(degI, chunkS, N);
    scan2_kernel<<<1, BS, 0, stream>>>(chunkS, chunkO, rowptr, C, N, (int)E);
    scan3_kernel<<<C, BS, 0, stream>>>(degI, chunkO, rowptr, cursor, N);
    fill_csr_kernel<<<gsBlocks, BS, 0, stream>>>(ei, cursor, csr_src, E);

    // ---- layer 1: tp1 = (x@W1)*dinv (bufA); h1 = gather+tanh (bufB) ----
    gemm_in_kernel<<<rowBlocks, BS, 0, stream>>>(x, W1, dinv, bufA, N);
    gather_tanh_kernel<<<rowBlocks, BS, 0, stream>>>(rowptr, csr_src, bufA, dinv, b1, bufB, N);
    extract_pooled_kernel<<<(G * LAT + BS - 1) / BS, BS, 0, stream>>>(bufB, idx, pooled, G, 0);

    // ---- layer 2: tp2 (bufA); h2 (bufB) ----
    gemm_lat_kernel<<<nvBlocks, BS, 0, stream>>>(bufB, W2, dinv, bufA, N);
    gather_tanh_kernel<<<rowBlocks, BS, 0, stream>>>(rowptr, csr_src, bufA, dinv, b2, bufB, N);
    extract_pooled_kernel<<<(G * LAT + BS - 1) / BS, BS, 0, stream>>>(bufB, idx, pooled, G, LAT);

    // ---- layer 3: tp3 (bufA); h3 (bufB) ----
    gemm_lat_kernel<<<nvBlocks, BS, 0, stream>>>(bufB, W3, dinv, bufA, N);
    gather_tanh_kernel<<<rowBlocks, BS, 0, stream>>>(rowptr, csr_src, bufA, dinv, b3, bufB, N);
    extract_pooled_kernel<<<(G * LAT + BS - 1) / BS, BS, 0, stream>>>(bufB, idx, pooled, G, 2 * LAT);

    // ---- MLP head ----
    mlp_head_kernel<<<G, HID, 0, stream>>>(pooled, Wl1, bl1, Wl2, bl2, out, G);
}

// Round 3
// 1008.809 us; speedup vs baseline: 2.4740x; 1.6574x over previous
//
#include <hip/hip_runtime.h>
#include <hip/hip_bf16.h>
#include <math.h>

#define IN_DIM 128
#define LAT 32
#define HID 128
#define RSHIFT 8          // nodes per bucket = 256
#define RANGE 256
#define KMAX 1024         // max buckets (N <= 262144)
#define PART_CH 16384     // edges per partition block

// ---------------- small setup kernels ----------------

__global__ void compute_idx_kernel(const int* __restrict__ batch, int* __restrict__ idx,
                                   int N, int G) {
    int g = blockIdx.x * blockDim.x + threadIdx.x;
    if (g >= G) return;
    int lo = 0, hi = N;
    while (lo < hi) {
        int mid = (lo + hi) >> 1;
        if (batch[mid] < g) lo = mid + 1; else hi = mid;
    }
    idx[g] = lo;
}

// ---------------- radix-partition CSR build ----------------

// bucket counts via per-block LDS histogram
__global__ void bucket_hist_kernel(const int* __restrict__ ei, int* __restrict__ bucketTot,
                                   long long E, int K) {
    __shared__ int hist[KMAX];
    for (int b = threadIdx.x; b < K; b += blockDim.x) hist[b] = 0;
    __syncthreads();
    long long tid = (long long)blockIdx.x * blockDim.x + threadIdx.x;
    long long stride = (long long)gridDim.x * blockDim.x;
    for (long long e = tid; e < E; e += stride) {
        int d = ei[E + e];
        atomicAdd(&hist[d >> RSHIFT], 1);
    }
    __syncthreads();
    for (int b = threadIdx.x; b < K; b += blockDim.x) {
        int h = hist[b];
        if (h) atomicAdd(&bucketTot[b], h);
    }
}

// single-block exclusive scan over K bucket totals
__global__ void bucket_scan_kernel(const int* __restrict__ bucketTot, int* __restrict__ bucketStart,
                                   int* __restrict__ bucketCursor, int K, int Etot,
                                   int* __restrict__ rowptr, int N) {
    __shared__ int s[KMAX];
    int t = threadIdx.x;
    int v = (t < K) ? bucketTot[t] : 0;
    s[t] = v;
    __syncthreads();
    for (int off = 1; off < KMAX; off <<= 1) {
        int tmp = (t >= off) ? s[t - off] : 0;
        __syncthreads();
        s[t] += tmp;
        __syncthreads();
    }
    if (t < K) {
        int excl = s[t] - v;
        bucketStart[t] = excl;
        bucketCursor[t] = excl;
    }
    if (t == 0) {
        bucketStart[K] = Etot;
        rowptr[N] = Etot;
    }
}

// scatter packed (src<<8 | dst&255) into bucket regions
__global__ void partition_kernel(const int* __restrict__ ei, int* __restrict__ bucketCursor,
                                 unsigned int* __restrict__ pairs, long long E, int K) {
    __shared__ int hist[KMAX];
    __shared__ int off[KMAX];
    __shared__ int cur[KMAX];
    int t = threadIdx.x;
    for (int b = t; b < K; b += blockDim.x) { hist[b] = 0; cur[b] = 0; }
    __syncthreads();
    long long e0 = (long long)blockIdx.x * PART_CH;
    int cnt = (int)min((long long)PART_CH, E - e0);
    for (int i = t; i < cnt; i += blockDim.x) {
        int d = ei[E + e0 + i];
        atomicAdd(&hist[d >> RSHIFT], 1);
    }
    __syncthreads();
    for (int b = t; b < K; b += blockDim.x) {
        int h = hist[b];
        off[b] = h ? atomicAdd(&bucketCursor[b], h) : 0;
    }
    __syncthreads();
    for (int i = t; i < cnt; i += blockDim.x) {
        long long e = e0 + i;
        unsigned int s = (unsigned int)ei[e];
        int d = ei[E + e];
        int b = d >> RSHIFT;
        int p = off[b] + atomicAdd(&cur[b], 1);
        pairs[p] = (s << RSHIFT) | (unsigned int)(d & (RANGE - 1));
    }
}

// one block per bucket: LDS hist + scan -> rowptr/dinv, then scatter csr_src
__global__ void build_csr_kernel(const unsigned int* __restrict__ pairs,
                                 const int* __restrict__ bucketStart,
                                 int* __restrict__ rowptr, float* __restrict__ dinv,
                                 int* __restrict__ csr_src, int N) {
    __shared__ int hist[RANGE];
    __shared__ int scanb[RANGE];
    __shared__ int cursor[RANGE];
    int b = blockIdx.x;
    int t = threadIdx.x;
    int base = b << RSHIFT;
    int s0 = bucketStart[b];
    int s1 = bucketStart[b + 1];
    int cnt = s1 - s0;
    hist[t] = 0;
    __syncthreads();
    for (int i = t; i < cnt; i += RANGE) {
        unsigned int p = pairs[s0 + i];
        atomicAdd(&hist[p & (RANGE - 1)], 1);
    }
    __syncthreads();
    int deg = hist[t];
    scanb[t] = deg;
    __syncthreads();
    for (int off = 1; off < RANGE; off <<= 1) {
        int tmp = (t >= off) ? scanb[t - off] : 0;
        __syncthreads();
        scanb[t] += tmp;
        __syncthreads();
    }
    int excl = scanb[t] - deg;
    int node = base + t;
    if (node < N) {
        rowptr[node] = s0 + excl;
        dinv[node] = rsqrtf((float)(deg + 1));   // +1 self-loop
    }
    cursor[t] = s0 + excl;
    __syncthreads();
    for (int i = t; i < cnt; i += RANGE) {
        unsigned int p = pairs[s0 + i];
        int slot = atomicAdd(&cursor[p & (RANGE - 1)], 1);
        csr_src[slot] = (int)(p >> RSHIFT);
    }
}

// ---------------- transforms (GEMM with dinv-scaled epilogue) ----------------

__global__ void gemm_in_kernel(const float* __restrict__ x, const float* __restrict__ W,
                               const float* __restrict__ dinv, float* __restrict__ tp, int N) {
    __shared__ float Wl[IN_DIM * LAT];
    for (int i = threadIdx.x; i < IN_DIM * LAT; i += blockDim.x) Wl[i] = W[i];
    __syncthreads();
    int r = blockIdx.x * 8 + (int)(threadIdx.x >> 5);
    int c = threadIdx.x & 31;
    if (r >= N) return;
    const float* xr = x + (long long)r * IN_DIM;
    float acc = 0.f;
#pragma unroll 8
    for (int k = 0; k < IN_DIM; k++) acc += xr[k] * Wl[k * LAT + c];
    tp[(long long)r * LAT + c] = acc * dinv[r];
}

__global__ void gemm_lat_kernel(const float* __restrict__ h, const float* __restrict__ W,
                                const float* __restrict__ dinv, float* __restrict__ tp, int N) {
    __shared__ float Wl[LAT * LAT];
    for (int i = threadIdx.x; i < LAT * LAT; i += blockDim.x) Wl[i] = W[i];
    __syncthreads();
    long long idx = (long long)blockIdx.x * blockDim.x + threadIdx.x;
    long long total = (long long)N * LAT;
    if (idx >= total) return;
    int v = (int)(idx >> 5);
    int c = (int)(idx & 31);
    const float* hr = h + (long long)v * LAT;
    float acc = 0.f;
#pragma unroll
    for (int k = 0; k < LAT; k++) acc += hr[k] * Wl[k * LAT + c];
    tp[idx] = acc * dinv[v];
}

// ---------------- gather-reduce aggregation + tanh ----------------

__global__ void gather_tanh_kernel(const int* __restrict__ rowptr, const int* __restrict__ csr_src,
                                   const float* __restrict__ tp, const float* __restrict__ dinv,
                                   const float* __restrict__ b, float* __restrict__ h, int N) {
    int v = blockIdx.x * 8 + (int)(threadIdx.x >> 5);
    int f = threadIdx.x & 31;
    if (v >= N) return;
    int start = rowptr[v];
    int end = rowptr[v + 1];
    float acc = tp[(long long)v * LAT + f];   // self-loop term
    for (int base = start; base < end; base += 32) {
        int e = base + f;
        int s = (e < end) ? csr_src[e] : 0;
        int cnt = min(32, end - base);
        for (int j = 0; j < cnt; j++) {
            int sj = __shfl(s, j, 32);
            acc += tp[(long long)sj * LAT + f];
        }
    }
    h[(long long)v * LAT + f] = tanhf(dinv[v] * acc + b[f]);
}

__global__ void extract_pooled_kernel(const float* __restrict__ h, const int* __restrict__ idx,
                                      float* __restrict__ pooled, int G, int col_off) {
    int tid = blockIdx.x * blockDim.x + threadIdx.x;
    if (tid >= G * LAT) return;
    int g = tid >> 5;
    int f = tid & 31;
    pooled[(long long)g * (3 * LAT) + col_off + f] = h[(long long)idx[g] * LAT + f];
}

// ---------------- MLP head ----------------

__global__ void mlp_head_kernel(const float* __restrict__ pooled,
                                const float* __restrict__ Wl1, const float* __restrict__ bl1,
                                const float* __restrict__ Wl2, const float* __restrict__ bl2,
                                float* __restrict__ out, int G) {
    __shared__ float prow[3 * LAT];
    __shared__ float red0[HID];
    __shared__ float red1[HID];
    int g = blockIdx.x;
    int j = threadIdx.x;
    if (j < 3 * LAT) prow[j] = pooled[(long long)g * (3 * LAT) + j];
    __syncthreads();
    float acc = bl1[j];
#pragma unroll 8
    for (int k = 0; k < 3 * LAT; k++) acc += prow[k] * Wl1[k * HID + j];
    float hj = fmaxf(acc, 0.f);
    red0[j] = hj * Wl2[j * 2 + 0];
    red1[j] = hj * Wl2[j * 2 + 1];
    __syncthreads();
    for (int s = HID / 2; s > 0; s >>= 1) {
        if (j < s) { red0[j] += red0[j + s]; red1[j] += red1[j + s]; }
        __syncthreads();
    }
    if (j == 0) {
        float l0 = red0[0] + bl2[0];
        float l1 = red1[0] + bl2[1];
        float m = fmaxf(l0, l1);
        float lse = m + logf(expf(l0 - m) + expf(l1 - m));
        out[(long long)g * 2 + 0] = l0 - lse;
        out[(long long)g * 2 + 1] = l1 - lse;
    }
}

// ---------------- launch ----------------

extern "C" void kernel_launch(void* const* d_in, const int* in_sizes, int n_in,
                              void* d_out, int out_size, void* d_ws, size_t ws_size,
                              hipStream_t stream) {
    const float* x    = (const float*)d_in[0];
    const int*   ei   = (const int*)d_in[1];
    const int*   batch= (const int*)d_in[2];
    const float* W1   = (const float*)d_in[3];
    const float* b1   = (const float*)d_in[4];
    const float* W2   = (const float*)d_in[5];
    const float* b2   = (const float*)d_in[6];
    const float* W3   = (const float*)d_in[7];
    const float* b3   = (const float*)d_in[8];
    const float* Wl1  = (const float*)d_in[9];
    const float* bl1  = (const float*)d_in[10];
    const float* Wl2  = (const float*)d_in[11];
    const float* bl2  = (const float*)d_in[12];
    float* out = (float*)d_out;

    const int N = in_sizes[2];
    const long long E = (long long)in_sizes[1] / 2;
    const int G = out_size / 2;
    const int K = (N + RANGE - 1) >> RSHIFT;   // buckets (782 for N=200K)

    // workspace layout
    char* ws = (char*)d_ws;
    size_t off = 0;
    float* bufA    = (float*)(ws + off); off += (size_t)N * LAT * 4;   // aliased by pairs
    float* bufB    = (float*)(ws + off); off += (size_t)N * LAT * 4;
    int*   csr_src = (int*)  (ws + off); off += (size_t)E * 4;
    float* dinv    = (float*)(ws + off); off += (size_t)N * 4;
    int*   rowptr  = (int*)  (ws + off); off += (size_t)(N + 1) * 4;
    int*   idx     = (int*)  (ws + off); off += (size_t)G * 4;
    float* pooled  = (float*)(ws + off); off += (size_t)G * (3 * LAT) * 4;
    int*   bucketTot    = (int*)(ws + off); off += (KMAX + 1) * 4;
    int*   bucketStart  = (int*)(ws + off); off += (KMAX + 1) * 4;
    int*   bucketCursor = (int*)(ws + off); off += KMAX * 4;

    unsigned int* pairs = (unsigned int*)bufA;   // E u32 == N*LAT*4 bytes; dead before gemm_in

    const int BS = 256;
    const int nvBlocks = (N * LAT + BS - 1) / BS;
    const int rowBlocks = (N + 7) / 8;
    const int partBlocks = (int)((E + PART_CH - 1) / PART_CH);

    // ---- CSR build via radix partition ----
    hipMemsetAsync(bucketTot, 0, (size_t)(KMAX + 1) * 4, stream);
    compute_idx_kernel<<<(G + BS - 1) / BS, BS, 0, stream>>>(batch, idx, N, G);
    bucket_hist_kernel<<<256, BS, 0, stream>>>(ei, bucketTot, E, K);
    bucket_scan_kernel<<<1, KMAX, 0, stream>>>(bucketTot, bucketStart, bucketCursor, K, (int)E, rowptr, N);
    partition_kernel<<<partBlocks, BS, 0, stream>>>(ei, bucketCursor, pairs, E, K);
    build_csr_kernel<<<K, RANGE, 0, stream>>>(pairs, bucketStart, rowptr, dinv, csr_src, N);

    // ---- layer 1 ----
    gemm_in_kernel<<<rowBlocks, BS, 0, stream>>>(x, W1, dinv, bufA, N);
    gather_tanh_kernel<<<rowBlocks, BS, 0, stream>>>(rowptr, csr_src, bufA, dinv, b1, bufB, N);
    extract_pooled_kernel<<<(G * LAT + BS - 1) / BS, BS, 0, stream>>>(bufB, idx, pooled, G, 0);

    // ---- layer 2 ----
    gemm_lat_kernel<<<nvBlocks, BS, 0, stream>>>(bufB, W2, dinv, bufA, N);
    gather_tanh_kernel<<<rowBlocks, BS, 0, stream>>>(rowptr, csr_src, bufA, dinv, b2, bufB, N);
    extract_pooled_kernel<<<(G * LAT + BS - 1) / BS, BS, 0, stream>>>(bufB, idx, pooled, G, LAT);

    // ---- layer 3 ----
    gemm_lat_kernel<<<nvBlocks, BS, 0, stream>>>(bufB, W3, dinv, bufA, N);
    gather_tanh_kernel<<<rowBlocks, BS, 0, stream>>>(rowptr, csr_src, bufA, dinv, b3, bufB, N);
    extract_pooled_kernel<<<(G * LAT + BS - 1) / BS, BS, 0, stream>>>(bufB, idx, pooled, G, 2 * LAT);

    // ---- MLP head ----
    mlp_head_kernel<<<G, HID, 0, stream>>>(pooled, Wl1, bl1, Wl2, bl2, out, G);
}

// Round 4
// 953.823 us; speedup vs baseline: 2.6166x; 1.0576x over previous
//
#include <hip/hip_runtime.h>
#include <hip/hip_bf16.h>
#include <math.h>

#define IN_DIM 128
#define LAT 32
#define HID 128
#define RSHIFT 8          // nodes per bucket = 256
#define RANGE 256
#define KMAX 1024
#define PART_CH 16384

typedef unsigned short u16;

__device__ __forceinline__ float bf2f(u16 v) {
    return __uint_as_float(((unsigned int)v) << 16);
}
__device__ __forceinline__ u16 f2bf(float f) {
    unsigned int u = __float_as_uint(f);
    u += 0x7fff + ((u >> 16) & 1);   // round-to-nearest-even
    return (u16)(u >> 16);
}

// ---------------- setup ----------------

// pmap[v] = graphId+1 if v is the first node of its graph, else 0
__global__ void pmap_kernel(const int* __restrict__ batch, int* __restrict__ pmap, int N) {
    int v = blockIdx.x * blockDim.x + threadIdx.x;
    if (v >= N) return;
    int b = batch[v];
    int prev = (v == 0) ? -1 : batch[v - 1];
    pmap[v] = (b != prev) ? (b + 1) : 0;
}

// ---------------- radix-partition CSR build ----------------

__global__ void bucket_hist_kernel(const int* __restrict__ ei, int* __restrict__ bucketTot,
                                   long long E, int K) {
    __shared__ int hist[KMAX];
    for (int b = threadIdx.x; b < K; b += blockDim.x) hist[b] = 0;
    __syncthreads();
    long long tid = (long long)blockIdx.x * blockDim.x + threadIdx.x;
    long long stride = (long long)gridDim.x * blockDim.x;
    for (long long e = tid; e < E; e += stride) {
        int d = ei[E + e];
        atomicAdd(&hist[d >> RSHIFT], 1);
    }
    __syncthreads();
    for (int b = threadIdx.x; b < K; b += blockDim.x) {
        int h = hist[b];
        if (h) atomicAdd(&bucketTot[b], h);
    }
}

__global__ void bucket_scan_kernel(const int* __restrict__ bucketTot, int* __restrict__ bucketStart,
                                   int* __restrict__ bucketCursor, int K, int Etot,
                                   int* __restrict__ rowptr, int N) {
    __shared__ int s[KMAX];
    int t = threadIdx.x;
    int v = (t < K) ? bucketTot[t] : 0;
    s[t] = v;
    __syncthreads();
    for (int off = 1; off < KMAX; off <<= 1) {
        int tmp = (t >= off) ? s[t - off] : 0;
        __syncthreads();
        s[t] += tmp;
        __syncthreads();
    }
    if (t < K) {
        int excl = s[t] - v;
        bucketStart[t] = excl;
        bucketCursor[t] = excl;
    }
    if (t == 0) {
        bucketStart[K] = Etot;
        rowptr[N] = Etot;
    }
}

__global__ void partition_kernel(const int* __restrict__ ei, int* __restrict__ bucketCursor,
                                 unsigned int* __restrict__ pairs, long long E, int K) {
    __shared__ int hist[KMAX];
    __shared__ int off[KMAX];
    __shared__ int cur[KMAX];
    int t = threadIdx.x;
    for (int b = t; b < K; b += blockDim.x) { hist[b] = 0; cur[b] = 0; }
    __syncthreads();
    long long e0 = (long long)blockIdx.x * PART_CH;
    int cnt = (int)min((long long)PART_CH, E - e0);
    for (int i = t; i < cnt; i += blockDim.x) {
        int d = ei[E + e0 + i];
        atomicAdd(&hist[d >> RSHIFT], 1);
    }
    __syncthreads();
    for (int b = t; b < K; b += blockDim.x) {
        int h = hist[b];
        off[b] = h ? atomicAdd(&bucketCursor[b], h) : 0;
    }
    __syncthreads();
    for (int i = t; i < cnt; i += blockDim.x) {
        long long e = e0 + i;
        unsigned int s = (unsigned int)ei[e];
        int d = ei[E + e];
        int b = d >> RSHIFT;
        int p = off[b] + atomicAdd(&cur[b], 1);
        pairs[p] = (s << RSHIFT) | (unsigned int)(d & (RANGE - 1));
    }
}

__global__ void build_csr_kernel(const unsigned int* __restrict__ pairs,
                                 const int* __restrict__ bucketStart,
                                 int* __restrict__ rowptr, float* __restrict__ dinv,
                                 int* __restrict__ csr_src, int N) {
    __shared__ int hist[RANGE];
    __shared__ int scanb[RANGE];
    __shared__ int cursor[RANGE];
    int b = blockIdx.x;
    int t = threadIdx.x;
    int base = b << RSHIFT;
    int s0 = bucketStart[b];
    int s1 = bucketStart[b + 1];
    int cnt = s1 - s0;
    hist[t] = 0;
    __syncthreads();
    for (int i = t; i < cnt; i += RANGE) {
        unsigned int p = pairs[s0 + i];
        atomicAdd(&hist[p & (RANGE - 1)], 1);
    }
    __syncthreads();
    int deg = hist[t];
    scanb[t] = deg;
    __syncthreads();
    for (int off = 1; off < RANGE; off <<= 1) {
        int tmp = (t >= off) ? scanb[t - off] : 0;
        __syncthreads();
        scanb[t] += tmp;
        __syncthreads();
    }
    int excl = scanb[t] - deg;
    int node = base + t;
    if (node < N) {
        rowptr[node] = s0 + excl;
        dinv[node] = rsqrtf((float)(deg + 1));   // +1 self-loop
    }
    cursor[t] = s0 + excl;
    __syncthreads();
    for (int i = t; i < cnt; i += RANGE) {
        unsigned int p = pairs[s0 + i];
        int slot = atomicAdd(&cursor[p & (RANGE - 1)], 1);
        csr_src[slot] = (int)(p >> RSHIFT);
    }
}

// ---------------- input transform: tp1 = (x@W1)*dinv, bf16 ----------------

__global__ void gemm_in_kernel(const float* __restrict__ x, const float* __restrict__ W,
                               const float* __restrict__ dinv, u16* __restrict__ tp, int N) {
    __shared__ float Wl[IN_DIM * LAT];
    for (int i = threadIdx.x; i < IN_DIM * LAT; i += blockDim.x) Wl[i] = W[i];
    __syncthreads();
    int r = blockIdx.x * 8 + (int)(threadIdx.x >> 5);
    int c = threadIdx.x & 31;
    if (r >= N) return;
    const float* xr = x + (long long)r * IN_DIM;
    float acc = 0.f;
#pragma unroll 8
    for (int k = 0; k < IN_DIM; k++) acc += xr[k] * Wl[k * LAT + c];
    tp[(long long)r * LAT + c] = f2bf(acc * dinv[r]);
}

// ---------------- fused gather + tanh + next-layer GEMM ----------------
// h[v,f] = tanh( dinv[v]*(sum_nbr tp[s,f] + tp[v,f]) + b[f] )     (lane-resident)
// pooled row written if v is a first-node; tpNext = (h@Wnext)*dinv (bf16) if Wnext

__global__ void gather_fused_kernel(const int* __restrict__ rowptr, const int* __restrict__ csr_src,
                                    const u16* __restrict__ tp, const float* __restrict__ dinv,
                                    const float* __restrict__ bcur, const int* __restrict__ pmap,
                                    float* __restrict__ pooled, int colOff,
                                    const float* __restrict__ Wnext, u16* __restrict__ tpNext,
                                    int N) {
    __shared__ float Wl[LAT * LAT];
    if (Wnext) {   // grid-uniform branch
        for (int i = threadIdx.x; i < LAT * LAT; i += blockDim.x) Wl[i] = Wnext[i];
        __syncthreads();
    }
    int v = blockIdx.x * 8 + (int)(threadIdx.x >> 5);
    int f = threadIdx.x & 31;
    if (v >= N) return;
    int start = rowptr[v];
    int end = rowptr[v + 1];
    float acc = bf2f(tp[(long long)v * LAT + f]);   // self-loop term
    for (int base = start; base < end; base += 32) {
        int e = base + f;
        int s = (e < end) ? csr_src[e] : 0;         // coalesced index load
        int cnt = min(32, end - base);
        for (int j = 0; j < cnt; j++) {
            int sj = __shfl(s, j, 32);
            acc += bf2f(tp[(long long)sj * LAT + f]);  // 64B row
        }
    }
    float dv = dinv[v];
    float hv = tanhf(dv * acc + bcur[f]);
    int pg = pmap[v];
    if (pg) pooled[(long long)(pg - 1) * (3 * LAT) + colOff + f] = hv;
    if (Wnext) {
        float acc2 = 0.f;
#pragma unroll
        for (int k = 0; k < LAT; k++) acc2 += __shfl(hv, k, 32) * Wl[k * LAT + f];
        tpNext[(long long)v * LAT + f] = f2bf(acc2 * dv);
    }
}

// ---------------- MLP head ----------------

__global__ void mlp_head_kernel(const float* __restrict__ pooled,
                                const float* __restrict__ Wl1, const float* __restrict__ bl1,
                                const float* __restrict__ Wl2, const float* __restrict__ bl2,
                                float* __restrict__ out, int G) {
    __shared__ float prow[3 * LAT];
    __shared__ float red0[HID];
    __shared__ float red1[HID];
    int g = blockIdx.x;
    int j = threadIdx.x;
    if (j < 3 * LAT) prow[j] = pooled[(long long)g * (3 * LAT) + j];
    __syncthreads();
    float acc = bl1[j];
#pragma unroll 8
    for (int k = 0; k < 3 * LAT; k++) acc += prow[k] * Wl1[k * HID + j];
    float hj = fmaxf(acc, 0.f);
    red0[j] = hj * Wl2[j * 2 + 0];
    red1[j] = hj * Wl2[j * 2 + 1];
    __syncthreads();
    for (int s = HID / 2; s > 0; s >>= 1) {
        if (j < s) { red0[j] += red0[j + s]; red1[j] += red1[j + s]; }
        __syncthreads();
    }
    if (j == 0) {
        float l0 = red0[0] + bl2[0];
        float l1 = red1[0] + bl2[1];
        float m = fmaxf(l0, l1);
        float lse = m + logf(expf(l0 - m) + expf(l1 - m));
        out[(long long)g * 2 + 0] = l0 - lse;
        out[(long long)g * 2 + 1] = l1 - lse;
    }
}

// ---------------- launch ----------------

extern "C" void kernel_launch(void* const* d_in, const int* in_sizes, int n_in,
                              void* d_out, int out_size, void* d_ws, size_t ws_size,
                              hipStream_t stream) {
    const float* x    = (const float*)d_in[0];
    const int*   ei   = (const int*)d_in[1];
    const int*   batch= (const int*)d_in[2];
    const float* W1   = (const float*)d_in[3];
    const float* b1   = (const float*)d_in[4];
    const float* W2   = (const float*)d_in[5];
    const float* b2   = (const float*)d_in[6];
    const float* W3   = (const float*)d_in[7];
    const float* b3   = (const float*)d_in[8];
    const float* Wl1  = (const float*)d_in[9];
    const float* bl1  = (const float*)d_in[10];
    const float* Wl2  = (const float*)d_in[11];
    const float* bl2  = (const float*)d_in[12];
    float* out = (float*)d_out;

    const int N = in_sizes[2];
    const long long E = (long long)in_sizes[1] / 2;
    const int G = out_size / 2;
    const int K = (N + RANGE - 1) >> RSHIFT;

    // workspace layout
    char* ws = (char*)d_ws;
    size_t off = 0;
    char*  bufA    = ws + off;           off += (size_t)E * 4;            // pairs (u32 E), later tpA (bf16 N*32)
    char*  bufB    = ws + off;           off += (size_t)N * LAT * 2;      // tpB (bf16)
    int*   csr_src = (int*)  (ws + off); off += (size_t)E * 4;
    float* dinv    = (float*)(ws + off); off += (size_t)N * 4;
    int*   rowptr  = (int*)  (ws + off); off += (size_t)(N + 1) * 4;
    int*   pmap    = (int*)  (ws + off); off += (size_t)N * 4;
    float* pooled  = (float*)(ws + off); off += (size_t)G * (3 * LAT) * 4;
    int*   bucketTot    = (int*)(ws + off); off += (KMAX + 1) * 4;
    int*   bucketStart  = (int*)(ws + off); off += (KMAX + 1) * 4;
    int*   bucketCursor = (int*)(ws + off); off += KMAX * 4;

    unsigned int* pairs = (unsigned int*)bufA;   // dead before gemm_in writes tpA
    u16* tpA = (u16*)bufA;
    u16* tpB = (u16*)bufB;

    const int BS = 256;
    const int rowBlocks = (N + 7) / 8;
    const int partBlocks = (int)((E + PART_CH - 1) / PART_CH);

    // ---- CSR build via radix partition ----
    hipMemsetAsync(bucketTot, 0, (size_t)(KMAX + 1) * 4, stream);
    pmap_kernel<<<(N + BS - 1) / BS, BS, 0, stream>>>(batch, pmap, N);
    bucket_hist_kernel<<<256, BS, 0, stream>>>(ei, bucketTot, E, K);
    bucket_scan_kernel<<<1, KMAX, 0, stream>>>(bucketTot, bucketStart, bucketCursor, K, (int)E, rowptr, N);
    partition_kernel<<<partBlocks, BS, 0, stream>>>(ei, bucketCursor, pairs, E, K);
    build_csr_kernel<<<K, RANGE, 0, stream>>>(pairs, bucketStart, rowptr, dinv, csr_src, N);

    // ---- layer 1 transform ----
    gemm_in_kernel<<<rowBlocks, BS, 0, stream>>>(x, W1, dinv, tpA, N);

    // ---- fused layers ----
    gather_fused_kernel<<<rowBlocks, BS, 0, stream>>>(rowptr, csr_src, tpA, dinv, b1, pmap,
                                                      pooled, 0, W2, tpB, N);
    gather_fused_kernel<<<rowBlocks, BS, 0, stream>>>(rowptr, csr_src, tpB, dinv, b2, pmap,
                                                      pooled, LAT, W3, tpA, N);
    gather_fused_kernel<<<rowBlocks, BS, 0, stream>>>(rowptr, csr_src, tpA, dinv, b3, pmap,
                                                      pooled, 2 * LAT, (const float*)nullptr,
                                                      (u16*)nullptr, N);

    // ---- MLP head ----
    mlp_head_kernel<<<G, HID, 0, stream>>>(pooled, Wl1, bl1, Wl2, bl2, out, G);
}

// Round 5
// 744.618 us; speedup vs baseline: 3.3517x; 1.2810x over previous
//
#include <hip/hip_runtime.h>
#include <hip/hip_bf16.h>
#include <math.h>

#define IN_DIM 128
#define LAT 32
#define HID 128
#define RSHIFT 8          // nodes per bucket = 256
#define RANGE 256
#define KMAX 1024
#define PART_CH 16384

typedef unsigned short u16;

__device__ __forceinline__ float bf2f(u16 v) {
    return __uint_as_float(((unsigned int)v) << 16);
}
__device__ __forceinline__ u16 f2bf(float f) {
    unsigned int u = __float_as_uint(f);
    u += 0x7fff + ((u >> 16) & 1);   // round-to-nearest-even
    return (u16)(u >> 16);
}

// ---------------- setup ----------------

__global__ void pmap_kernel(const int* __restrict__ batch, int* __restrict__ pmap, int N) {
    int v = blockIdx.x * blockDim.x + threadIdx.x;
    if (v >= N) return;
    int b = batch[v];
    int prev = (v == 0) ? -1 : batch[v - 1];
    pmap[v] = (b != prev) ? (b + 1) : 0;
}

// ---------------- radix-partition CSR build ----------------

__global__ void bucket_hist_kernel(const int* __restrict__ ei, int* __restrict__ bucketTot,
                                   long long E, int K) {
    __shared__ int hist[KMAX];
    for (int b = threadIdx.x; b < K; b += blockDim.x) hist[b] = 0;
    __syncthreads();
    long long tid = (long long)blockIdx.x * blockDim.x + threadIdx.x;
    long long stride = (long long)gridDim.x * blockDim.x;
    for (long long e = tid; e < E; e += stride) {
        int d = ei[E + e];
        atomicAdd(&hist[d >> RSHIFT], 1);
    }
    __syncthreads();
    for (int b = threadIdx.x; b < K; b += blockDim.x) {
        int h = hist[b];
        if (h) atomicAdd(&bucketTot[b], h);
    }
}

__global__ void bucket_scan_kernel(const int* __restrict__ bucketTot, int* __restrict__ bucketStart,
                                   int* __restrict__ bucketCursor, int K, int Etot,
                                   int* __restrict__ rowptr, int N) {
    __shared__ int s[KMAX];
    int t = threadIdx.x;
    int v = (t < K) ? bucketTot[t] : 0;
    s[t] = v;
    __syncthreads();
    for (int off = 1; off < KMAX; off <<= 1) {
        int tmp = (t >= off) ? s[t - off] : 0;
        __syncthreads();
        s[t] += tmp;
        __syncthreads();
    }
    if (t < K) {
        int excl = s[t] - v;
        bucketStart[t] = excl;
        bucketCursor[t] = excl;
    }
    if (t == 0) {
        bucketStart[K] = Etot;
        rowptr[N] = Etot;
    }
}

__global__ void partition_kernel(const int* __restrict__ ei, int* __restrict__ bucketCursor,
                                 unsigned int* __restrict__ pairs, long long E, int K) {
    __shared__ int hist[KMAX];
    __shared__ int off[KMAX];
    __shared__ int cur[KMAX];
    int t = threadIdx.x;
    for (int b = t; b < K; b += blockDim.x) { hist[b] = 0; cur[b] = 0; }
    __syncthreads();
    long long e0 = (long long)blockIdx.x * PART_CH;
    int cnt = (int)min((long long)PART_CH, E - e0);
    for (int i = t; i < cnt; i += blockDim.x) {
        int d = ei[E + e0 + i];
        atomicAdd(&hist[d >> RSHIFT], 1);
    }
    __syncthreads();
    for (int b = t; b < K; b += blockDim.x) {
        int h = hist[b];
        off[b] = h ? atomicAdd(&bucketCursor[b], h) : 0;
    }
    __syncthreads();
    for (int i = t; i < cnt; i += blockDim.x) {
        long long e = e0 + i;
        unsigned int s = (unsigned int)ei[e];
        int d = ei[E + e];
        int b = d >> RSHIFT;
        int p = off[b] + atomicAdd(&cur[b], 1);
        pairs[p] = (s << RSHIFT) | (unsigned int)(d & (RANGE - 1));
    }
}

__global__ void build_csr_kernel(const unsigned int* __restrict__ pairs,
                                 const int* __restrict__ bucketStart,
                                 int* __restrict__ rowptr, float* __restrict__ dinv,
                                 int* __restrict__ csr_src, int N) {
    __shared__ int hist[RANGE];
    __shared__ int scanb[RANGE];
    __shared__ int cursor[RANGE];
    int b = blockIdx.x;
    int t = threadIdx.x;
    int base = b << RSHIFT;
    int s0 = bucketStart[b];
    int s1 = bucketStart[b + 1];
    int cnt = s1 - s0;
    hist[t] = 0;
    __syncthreads();
    for (int i = t; i < cnt; i += RANGE) {
        unsigned int p = pairs[s0 + i];
        atomicAdd(&hist[p & (RANGE - 1)], 1);
    }
    __syncthreads();
    int deg = hist[t];
    scanb[t] = deg;
    __syncthreads();
    for (int off = 1; off < RANGE; off <<= 1) {
        int tmp = (t >= off) ? scanb[t - off] : 0;
        __syncthreads();
        scanb[t] += tmp;
        __syncthreads();
    }
    int excl = scanb[t] - deg;
    int node = base + t;
    if (node < N) {
        rowptr[node] = s0 + excl;
        dinv[node] = rsqrtf((float)(deg + 1));   // +1 self-loop
    }
    cursor[t] = s0 + excl;
    __syncthreads();
    for (int i = t; i < cnt; i += RANGE) {
        unsigned int p = pairs[s0 + i];
        int slot = atomicAdd(&cursor[p & (RANGE - 1)], 1);
        csr_src[slot] = (int)(p >> RSHIFT);
    }
}

// ---------------- input transform: tp1 = (x@W1)*dinv, bf16 ----------------

__global__ void gemm_in_kernel(const float* __restrict__ x, const float* __restrict__ W,
                               const float* __restrict__ dinv, u16* __restrict__ tp, int N) {
    __shared__ float Wl[IN_DIM * LAT];
    for (int i = threadIdx.x; i < IN_DIM * LAT; i += blockDim.x) Wl[i] = W[i];
    __syncthreads();
    int r = blockIdx.x * 8 + (int)(threadIdx.x >> 5);
    int c = threadIdx.x & 31;
    if (r >= N) return;
    const float* xr = x + (long long)r * IN_DIM;
    float acc = 0.f;
#pragma unroll 8
    for (int k = 0; k < IN_DIM; k++) acc += xr[k] * Wl[k * LAT + c];
    tp[(long long)r * LAT + c] = f2bf(acc * dinv[r]);
}

// ---------------- fused gather + tanh + next-layer GEMM ----------------
// Inner loop unrolled x8: batch 8 independent row loads to raise MLP
// (round-4 evidence: latency-bound at VGPR=20, 1 row in flight per half-wave)

__global__ void gather_fused_kernel(const int* __restrict__ rowptr, const int* __restrict__ csr_src,
                                    const u16* __restrict__ tp, const float* __restrict__ dinv,
                                    const float* __restrict__ bcur, const int* __restrict__ pmap,
                                    float* __restrict__ pooled, int colOff,
                                    const float* __restrict__ Wnext, u16* __restrict__ tpNext,
                                    int N) {
    __shared__ float Wl[LAT * LAT];
    if (Wnext) {   // grid-uniform branch
        for (int i = threadIdx.x; i < LAT * LAT; i += blockDim.x) Wl[i] = Wnext[i];
        __syncthreads();
    }
    int v = blockIdx.x * 8 + (int)(threadIdx.x >> 5);
    int f = threadIdx.x & 31;
    if (v >= N) return;
    int start = rowptr[v];
    int end = rowptr[v + 1];
    float acc = bf2f(tp[(long long)v * LAT + f]);   // self-loop term
    int e = start;
    // full 32-edge blocks, 8 rows in flight
    for (; e + 32 <= end; e += 32) {
        int s = csr_src[e + f];                     // coalesced index load
#pragma unroll
        for (int jj = 0; jj < 32; jj += 8) {
            int s0 = __shfl(s, jj + 0, 32), s1 = __shfl(s, jj + 1, 32);
            int s2 = __shfl(s, jj + 2, 32), s3 = __shfl(s, jj + 3, 32);
            int s4 = __shfl(s, jj + 4, 32), s5 = __shfl(s, jj + 5, 32);
            int s6 = __shfl(s, jj + 6, 32), s7 = __shfl(s, jj + 7, 32);
            float r0 = bf2f(tp[(long long)s0 * LAT + f]);
            float r1 = bf2f(tp[(long long)s1 * LAT + f]);
            float r2 = bf2f(tp[(long long)s2 * LAT + f]);
            float r3 = bf2f(tp[(long long)s3 * LAT + f]);
            float r4 = bf2f(tp[(long long)s4 * LAT + f]);
            float r5 = bf2f(tp[(long long)s5 * LAT + f]);
            float r6 = bf2f(tp[(long long)s6 * LAT + f]);
            float r7 = bf2f(tp[(long long)s7 * LAT + f]);
            acc += ((r0 + r1) + (r2 + r3)) + ((r4 + r5) + (r6 + r7));
        }
    }
    // tail (< 32 edges), 4 rows in flight
    int rem = end - e;
    if (rem > 0) {
        int s = (f < rem) ? csr_src[e + f] : 0;
        int j = 0;
        for (; j + 4 <= rem; j += 4) {
            int s0 = __shfl(s, j + 0, 32), s1 = __shfl(s, j + 1, 32);
            int s2 = __shfl(s, j + 2, 32), s3 = __shfl(s, j + 3, 32);
            float r0 = bf2f(tp[(long long)s0 * LAT + f]);
            float r1 = bf2f(tp[(long long)s1 * LAT + f]);
            float r2 = bf2f(tp[(long long)s2 * LAT + f]);
            float r3 = bf2f(tp[(long long)s3 * LAT + f]);
            acc += (r0 + r1) + (r2 + r3);
        }
        for (; j < rem; j++) {
            int sj = __shfl(s, j, 32);
            acc += bf2f(tp[(long long)sj * LAT + f]);
        }
    }
    float dv = dinv[v];
    float hv = tanhf(dv * acc + bcur[f]);
    int pg = pmap[v];
    if (pg) pooled[(long long)(pg - 1) * (3 * LAT) + colOff + f] = hv;
    if (Wnext) {
        float acc2 = 0.f;
#pragma unroll
        for (int k = 0; k < LAT; k++) acc2 += __shfl(hv, k, 32) * Wl[k * LAT + f];
        tpNext[(long long)v * LAT + f] = f2bf(acc2 * dv);
    }
}

// ---------------- MLP head ----------------

__global__ void mlp_head_kernel(const float* __restrict__ pooled,
                                const float* __restrict__ Wl1, const float* __restrict__ bl1,
                                const float* __restrict__ Wl2, const float* __restrict__ bl2,
                                float* __restrict__ out, int G) {
    __shared__ float prow[3 * LAT];
    __shared__ float red0[HID];
    __shared__ float red1[HID];
    int g = blockIdx.x;
    int j = threadIdx.x;
    if (j < 3 * LAT) prow[j] = pooled[(long long)g * (3 * LAT) + j];
    __syncthreads();
    float acc = bl1[j];
#pragma unroll 8
    for (int k = 0; k < 3 * LAT; k++) acc += prow[k] * Wl1[k * HID + j];
    float hj = fmaxf(acc, 0.f);
    red0[j] = hj * Wl2[j * 2 + 0];
    red1[j] = hj * Wl2[j * 2 + 1];
    __syncthreads();
    for (int s = HID / 2; s > 0; s >>= 1) {
        if (j < s) { red0[j] += red0[j + s]; red1[j] += red1[j + s]; }
        __syncthreads();
    }
    if (j == 0) {
        float l0 = red0[0] + bl2[0];
        float l1 = red1[0] + bl2[1];
        float m = fmaxf(l0, l1);
        float lse = m + logf(expf(l0 - m) + expf(l1 - m));
        out[(long long)g * 2 + 0] = l0 - lse;
        out[(long long)g * 2 + 1] = l1 - lse;
    }
}

// ---------------- launch ----------------

extern "C" void kernel_launch(void* const* d_in, const int* in_sizes, int n_in,
                              void* d_out, int out_size, void* d_ws, size_t ws_size,
                              hipStream_t stream) {
    const float* x    = (const float*)d_in[0];
    const int*   ei   = (const int*)d_in[1];
    const int*   batch= (const int*)d_in[2];
    const float* W1   = (const float*)d_in[3];
    const float* b1   = (const float*)d_in[4];
    const float* W2   = (const float*)d_in[5];
    const float* b2   = (const float*)d_in[6];
    const float* W3   = (const float*)d_in[7];
    const float* b3   = (const float*)d_in[8];
    const float* Wl1  = (const float*)d_in[9];
    const float* bl1  = (const float*)d_in[10];
    const float* Wl2  = (const float*)d_in[11];
    const float* bl2  = (const float*)d_in[12];
    float* out = (float*)d_out;

    const int N = in_sizes[2];
    const long long E = (long long)in_sizes[1] / 2;
    const int G = out_size / 2;
    const int K = (N + RANGE - 1) >> RSHIFT;

    // workspace layout
    char* ws = (char*)d_ws;
    size_t off = 0;
    char*  bufA    = ws + off;           off += (size_t)E * 4;            // pairs (u32 E), later tpA (bf16 N*32)
    char*  bufB    = ws + off;           off += (size_t)N * LAT * 2;      // tpB (bf16)
    int*   csr_src = (int*)  (ws + off); off += (size_t)E * 4;
    float* dinv    = (float*)(ws + off); off += (size_t)N * 4;
    int*   rowptr  = (int*)  (ws + off); off += (size_t)(N + 1) * 4;
    int*   pmap    = (int*)  (ws + off); off += (size_t)N * 4;
    float* pooled  = (float*)(ws + off); off += (size_t)G * (3 * LAT) * 4;
    int*   bucketTot    = (int*)(ws + off); off += (KMAX + 1) * 4;
    int*   bucketStart  = (int*)(ws + off); off += (KMAX + 1) * 4;
    int*   bucketCursor = (int*)(ws + off); off += KMAX * 4;

    unsigned int* pairs = (unsigned int*)bufA;   // dead before gemm_in writes tpA
    u16* tpA = (u16*)bufA;
    u16* tpB = (u16*)bufB;

    const int BS = 256;
    const int rowBlocks = (N + 7) / 8;
    const int partBlocks = (int)((E + PART_CH - 1) / PART_CH);

    // ---- CSR build via radix partition ----
    hipMemsetAsync(bucketTot, 0, (size_t)(KMAX + 1) * 4, stream);
    pmap_kernel<<<(N + BS - 1) / BS, BS, 0, stream>>>(batch, pmap, N);
    bucket_hist_kernel<<<256, BS, 0, stream>>>(ei, bucketTot, E, K);
    bucket_scan_kernel<<<1, KMAX, 0, stream>>>(bucketTot, bucketStart, bucketCursor, K, (int)E, rowptr, N);
    partition_kernel<<<partBlocks, BS, 0, stream>>>(ei, bucketCursor, pairs, E, K);
    build_csr_kernel<<<K, RANGE, 0, stream>>>(pairs, bucketStart, rowptr, dinv, csr_src, N);

    // ---- layer 1 transform ----
    gemm_in_kernel<<<rowBlocks, BS, 0, stream>>>(x, W1, dinv, tpA, N);

    // ---- fused layers ----
    gather_fused_kernel<<<rowBlocks, BS, 0, stream>>>(rowptr, csr_src, tpA, dinv, b1, pmap,
                                                      pooled, 0, W2, tpB, N);
    gather_fused_kernel<<<rowBlocks, BS, 0, stream>>>(rowptr, csr_src, tpB, dinv, b2, pmap,
                                                      pooled, LAT, W3, tpA, N);
    gather_fused_kernel<<<rowBlocks, BS, 0, stream>>>(rowptr, csr_src, tpA, dinv, b3, pmap,
                                                      pooled, 2 * LAT, (const float*)nullptr,
                                                      (u16*)nullptr, N);

    // ---- MLP head ----
    mlp_head_kernel<<<G, HID, 0, stream>>>(pooled, Wl1, bl1, Wl2, bl2, out, G);
}

// Round 6
// 723.115 us; speedup vs baseline: 3.4514x; 1.0297x over previous
//
#include <hip/hip_runtime.h>
#include <hip/hip_bf16.h>
#include <math.h>

#define IN_DIM 128
#define LAT 32
#define HID 128
#define RSHIFT 8          // nodes per bucket = 256
#define RANGE 256
#define KMAX 1024
#define PART_CH 16384
#define GIN_ROWS 32       // rows per block in gemm_in

typedef unsigned short u16;

__device__ __forceinline__ float bf2f(u16 v) {
    return __uint_as_float(((unsigned int)v) << 16);
}
__device__ __forceinline__ u16 f2bf(float f) {
    unsigned int u = __float_as_uint(f);
    u += 0x7fff + ((u >> 16) & 1);   // round-to-nearest-even
    return (u16)(u >> 16);
}

// ---------------- setup ----------------

__global__ void pmap_kernel(const int* __restrict__ batch, int* __restrict__ pmap, int N) {
    int v = blockIdx.x * blockDim.x + threadIdx.x;
    if (v >= N) return;
    int b = batch[v];
    int prev = (v == 0) ? -1 : batch[v - 1];
    pmap[v] = (b != prev) ? (b + 1) : 0;
}

// ---------------- radix-partition CSR build ----------------

__global__ void bucket_hist_kernel(const int* __restrict__ ei, int* __restrict__ bucketTot,
                                   long long E, int K) {
    __shared__ int hist[KMAX];
    for (int b = threadIdx.x; b < K; b += blockDim.x) hist[b] = 0;
    __syncthreads();
    long long tid = (long long)blockIdx.x * blockDim.x + threadIdx.x;
    long long stride = (long long)gridDim.x * blockDim.x;
    for (long long e = tid; e < E; e += stride) {
        int d = ei[E + e];
        atomicAdd(&hist[d >> RSHIFT], 1);
    }
    __syncthreads();
    for (int b = threadIdx.x; b < K; b += blockDim.x) {
        int h = hist[b];
        if (h) atomicAdd(&bucketTot[b], h);
    }
}

__global__ void bucket_scan_kernel(const int* __restrict__ bucketTot, int* __restrict__ bucketStart,
                                   int* __restrict__ bucketCursor, int K, int Etot,
                                   int* __restrict__ rowptr, int N) {
    __shared__ int s[KMAX];
    int t = threadIdx.x;
    int v = (t < K) ? bucketTot[t] : 0;
    s[t] = v;
    __syncthreads();
    for (int off = 1; off < KMAX; off <<= 1) {
        int tmp = (t >= off) ? s[t - off] : 0;
        __syncthreads();
        s[t] += tmp;
        __syncthreads();
    }
    if (t < K) {
        int excl = s[t] - v;
        bucketStart[t] = excl;
        bucketCursor[t] = excl;
    }
    if (t == 0) {
        bucketStart[K] = Etot;
        rowptr[N] = Etot;
    }
}

__global__ void partition_kernel(const int* __restrict__ ei, int* __restrict__ bucketCursor,
                                 unsigned int* __restrict__ pairs, long long E, int K) {
    __shared__ int hist[KMAX];
    __shared__ int off[KMAX];
    __shared__ int cur[KMAX];
    int t = threadIdx.x;
    for (int b = t; b < K; b += blockDim.x) { hist[b] = 0; cur[b] = 0; }
    __syncthreads();
    long long e0 = (long long)blockIdx.x * PART_CH;
    int cnt = (int)min((long long)PART_CH, E - e0);
    for (int i = t; i < cnt; i += blockDim.x) {
        int d = ei[E + e0 + i];
        atomicAdd(&hist[d >> RSHIFT], 1);
    }
    __syncthreads();
    for (int b = t; b < K; b += blockDim.x) {
        int h = hist[b];
        off[b] = h ? atomicAdd(&bucketCursor[b], h) : 0;
    }
    __syncthreads();
    for (int i = t; i < cnt; i += blockDim.x) {
        long long e = e0 + i;
        unsigned int s = (unsigned int)ei[e];
        int d = ei[E + e];
        int b = d >> RSHIFT;
        int p = off[b] + atomicAdd(&cur[b], 1);
        pairs[p] = (s << RSHIFT) | (unsigned int)(d & (RANGE - 1));
    }
}

__global__ void build_csr_kernel(const unsigned int* __restrict__ pairs,
                                 const int* __restrict__ bucketStart,
                                 int* __restrict__ rowptr, float* __restrict__ dinv,
                                 int* __restrict__ csr_src, int N) {
    __shared__ int hist[RANGE];
    __shared__ int scanb[RANGE];
    __shared__ int cursor[RANGE];
    int b = blockIdx.x;
    int t = threadIdx.x;
    int base = b << RSHIFT;
    int s0 = bucketStart[b];
    int s1 = bucketStart[b + 1];
    int cnt = s1 - s0;
    hist[t] = 0;
    __syncthreads();
    for (int i = t; i < cnt; i += RANGE) {
        unsigned int p = pairs[s0 + i];
        atomicAdd(&hist[p & (RANGE - 1)], 1);
    }
    __syncthreads();
    int deg = hist[t];
    scanb[t] = deg;
    __syncthreads();
    for (int off = 1; off < RANGE; off <<= 1) {
        int tmp = (t >= off) ? scanb[t - off] : 0;
        __syncthreads();
        scanb[t] += tmp;
        __syncthreads();
    }
    int excl = scanb[t] - deg;
    int node = base + t;
    if (node < N) {
        rowptr[node] = s0 + excl;
        dinv[node] = rsqrtf((float)(deg + 1));   // +1 self-loop
    }
    cursor[t] = s0 + excl;
    __syncthreads();
    for (int i = t; i < cnt; i += RANGE) {
        unsigned int p = pairs[s0 + i];
        int slot = atomicAdd(&cursor[p & (RANGE - 1)], 1);
        csr_src[slot] = (int)(p >> RSHIFT);
    }
}

// ---------------- input transform: tp1 = (x@W1)*dinv, bf16 ----------------
// LDS-staged, 4-row x 1-col micro-tile per thread. Round-5 evidence: the
// scalar-load version was latency-bound (174us, VALUBusy 23%, 376 GB/s).

__global__ void gemm_in_kernel(const float* __restrict__ x, const float* __restrict__ W,
                               const float* __restrict__ dinv, u16* __restrict__ tp, int N) {
    __shared__ float Wl[IN_DIM * LAT];         // 16 KB
    __shared__ float Xl[GIN_ROWS * IN_DIM];    // 16 KB
    int t = threadIdx.x;
    for (int i = t; i < IN_DIM * LAT; i += 256) Wl[i] = W[i];
    long long rowBase = (long long)blockIdx.x * GIN_ROWS;
    int nrow = min(GIN_ROWS, (int)(N - rowBase));
    {
        const float4* x4 = reinterpret_cast<const float4*>(x + rowBase * IN_DIM);
        float4* X4 = reinterpret_cast<float4*>(Xl);
        int nf4 = nrow * (IN_DIM / 4);
        for (int i = t; i < nf4; i += 256) X4[i] = x4[i];   // coalesced
    }
    __syncthreads();
    int g = t >> 5;            // col-group 0..7
    int c = t & 31;
    int r0 = g * 4;            // 4 local rows per group
    float acc0 = 0.f, acc1 = 0.f, acc2 = 0.f, acc3 = 0.f;
#pragma unroll 4
    for (int k = 0; k < IN_DIM; k += 4) {
        float w0 = Wl[(k + 0) * LAT + c];      // bank = c, conflict-free
        float w1 = Wl[(k + 1) * LAT + c];
        float w2 = Wl[(k + 2) * LAT + c];
        float w3 = Wl[(k + 3) * LAT + c];
        float4 xa = *reinterpret_cast<const float4*>(&Xl[(r0 + 0) * IN_DIM + k]); // broadcast
        float4 xb = *reinterpret_cast<const float4*>(&Xl[(r0 + 1) * IN_DIM + k]);
        float4 xc = *reinterpret_cast<const float4*>(&Xl[(r0 + 2) * IN_DIM + k]);
        float4 xd = *reinterpret_cast<const float4*>(&Xl[(r0 + 3) * IN_DIM + k]);
        acc0 += xa.x * w0 + xa.y * w1 + xa.z * w2 + xa.w * w3;
        acc1 += xb.x * w0 + xb.y * w1 + xb.z * w2 + xb.w * w3;
        acc2 += xc.x * w0 + xc.y * w1 + xc.z * w2 + xc.w * w3;
        acc3 += xd.x * w0 + xd.y * w1 + xd.z * w2 + xd.w * w3;
    }
    long long rr = rowBase + r0;
    if (r0 + 0 < nrow) tp[(rr + 0) * LAT + c] = f2bf(acc0 * dinv[rr + 0]);
    if (r0 + 1 < nrow) tp[(rr + 1) * LAT + c] = f2bf(acc1 * dinv[rr + 1]);
    if (r0 + 2 < nrow) tp[(rr + 2) * LAT + c] = f2bf(acc2 * dinv[rr + 2]);
    if (r0 + 3 < nrow) tp[(rr + 3) * LAT + c] = f2bf(acc3 * dinv[rr + 3]);
}

// ---------------- fused gather + tanh + next-layer GEMM ----------------
// 32 rows in flight per edge-block (round-5: still MLP-limited at 8-deep)

__global__ void gather_fused_kernel(const int* __restrict__ rowptr, const int* __restrict__ csr_src,
                                    const u16* __restrict__ tp, const float* __restrict__ dinv,
                                    const float* __restrict__ bcur, const int* __restrict__ pmap,
                                    float* __restrict__ pooled, int colOff,
                                    const float* __restrict__ Wnext, u16* __restrict__ tpNext,
                                    int N) {
    __shared__ float Wl[LAT * LAT];
    if (Wnext) {   // grid-uniform branch
        for (int i = threadIdx.x; i < LAT * LAT; i += blockDim.x) Wl[i] = Wnext[i];
        __syncthreads();
    }
    int v = blockIdx.x * 8 + (int)(threadIdx.x >> 5);
    int f = threadIdx.x & 31;
    if (v >= N) return;
    int start = rowptr[v];
    int end = rowptr[v + 1];
    float acc = bf2f(tp[(long long)v * LAT + f]);   // self-loop term
    int e = start;
    // full 32-edge blocks: issue all 32 row loads before accumulating
    for (; e + 32 <= end; e += 32) {
        int s = csr_src[e + f];                     // coalesced index load
        float r[32];
#pragma unroll
        for (int j = 0; j < 32; j++) {
            int sj = __shfl(s, j, 32);
            r[j] = bf2f(tp[(long long)sj * LAT + f]);
        }
        float sum = 0.f;
#pragma unroll
        for (int j = 0; j < 32; j++) sum += r[j];
        acc += sum;
    }
    // tail (< 32 edges), 4 rows in flight
    int rem = end - e;
    if (rem > 0) {
        int s = (f < rem) ? csr_src[e + f] : 0;
        int j = 0;
        for (; j + 4 <= rem; j += 4) {
            int s0 = __shfl(s, j + 0, 32), s1 = __shfl(s, j + 1, 32);
            int s2 = __shfl(s, j + 2, 32), s3 = __shfl(s, j + 3, 32);
            float r0 = bf2f(tp[(long long)s0 * LAT + f]);
            float r1 = bf2f(tp[(long long)s1 * LAT + f]);
            float r2 = bf2f(tp[(long long)s2 * LAT + f]);
            float r3 = bf2f(tp[(long long)s3 * LAT + f]);
            acc += (r0 + r1) + (r2 + r3);
        }
        for (; j < rem; j++) {
            int sj = __shfl(s, j, 32);
            acc += bf2f(tp[(long long)sj * LAT + f]);
        }
    }
    float dv = dinv[v];
    float hv = tanhf(dv * acc + bcur[f]);
    int pg = pmap[v];
    if (pg) pooled[(long long)(pg - 1) * (3 * LAT) + colOff + f] = hv;
    if (Wnext) {
        float acc2 = 0.f;
#pragma unroll
        for (int k = 0; k < LAT; k++) acc2 += __shfl(hv, k, 32) * Wl[k * LAT + f];
        tpNext[(long long)v * LAT + f] = f2bf(acc2 * dv);
    }
}

// ---------------- MLP head ----------------

__global__ void mlp_head_kernel(const float* __restrict__ pooled,
                                const float* __restrict__ Wl1, const float* __restrict__ bl1,
                                const float* __restrict__ Wl2, const float* __restrict__ bl2,
                                float* __restrict__ out, int G) {
    __shared__ float prow[3 * LAT];
    __shared__ float red0[HID];
    __shared__ float red1[HID];
    int g = blockIdx.x;
    int j = threadIdx.x;
    if (j < 3 * LAT) prow[j] = pooled[(long long)g * (3 * LAT) + j];
    __syncthreads();
    float acc = bl1[j];
#pragma unroll 8
    for (int k = 0; k < 3 * LAT; k++) acc += prow[k] * Wl1[k * HID + j];
    float hj = fmaxf(acc, 0.f);
    red0[j] = hj * Wl2[j * 2 + 0];
    red1[j] = hj * Wl2[j * 2 + 1];
    __syncthreads();
    for (int s = HID / 2; s > 0; s >>= 1) {
        if (j < s) { red0[j] += red0[j + s]; red1[j] += red1[j + s]; }
        __syncthreads();
    }
    if (j == 0) {
        float l0 = red0[0] + bl2[0];
        float l1 = red1[0] + bl2[1];
        float m = fmaxf(l0, l1);
        float lse = m + logf(expf(l0 - m) + expf(l1 - m));
        out[(long long)g * 2 + 0] = l0 - lse;
        out[(long long)g * 2 + 1] = l1 - lse;
    }
}

// ---------------- launch ----------------

extern "C" void kernel_launch(void* const* d_in, const int* in_sizes, int n_in,
                              void* d_out, int out_size, void* d_ws, size_t ws_size,
                              hipStream_t stream) {
    const float* x    = (const float*)d_in[0];
    const int*   ei   = (const int*)d_in[1];
    const int*   batch= (const int*)d_in[2];
    const float* W1   = (const float*)d_in[3];
    const float* b1   = (const float*)d_in[4];
    const float* W2   = (const float*)d_in[5];
    const float* b2   = (const float*)d_in[6];
    const float* W3   = (const float*)d_in[7];
    const float* b3   = (const float*)d_in[8];
    const float* Wl1  = (const float*)d_in[9];
    const float* bl1  = (const float*)d_in[10];
    const float* Wl2  = (const float*)d_in[11];
    const float* bl2  = (const float*)d_in[12];
    float* out = (float*)d_out;

    const int N = in_sizes[2];
    const long long E = (long long)in_sizes[1] / 2;
    const int G = out_size / 2;
    const int K = (N + RANGE - 1) >> RSHIFT;

    // workspace layout
    char* ws = (char*)d_ws;
    size_t off = 0;
    char*  bufA    = ws + off;           off += (size_t)E * 4;            // pairs (u32 E), later tpA (bf16 N*32)
    char*  bufB    = ws + off;           off += (size_t)N * LAT * 2;      // tpB (bf16)
    int*   csr_src = (int*)  (ws + off); off += (size_t)E * 4;
    float* dinv    = (float*)(ws + off); off += (size_t)N * 4;
    int*   rowptr  = (int*)  (ws + off); off += (size_t)(N + 1) * 4;
    int*   pmap    = (int*)  (ws + off); off += (size_t)N * 4;
    float* pooled  = (float*)(ws + off); off += (size_t)G * (3 * LAT) * 4;
    int*   bucketTot    = (int*)(ws + off); off += (KMAX + 1) * 4;
    int*   bucketStart  = (int*)(ws + off); off += (KMAX + 1) * 4;
    int*   bucketCursor = (int*)(ws + off); off += KMAX * 4;

    unsigned int* pairs = (unsigned int*)bufA;   // dead before gemm_in writes tpA
    u16* tpA = (u16*)bufA;
    u16* tpB = (u16*)bufB;

    const int BS = 256;
    const int rowBlocks = (N + 7) / 8;
    const int ginBlocks = (N + GIN_ROWS - 1) / GIN_ROWS;
    const int partBlocks = (int)((E + PART_CH - 1) / PART_CH);

    // ---- CSR build via radix partition ----
    hipMemsetAsync(bucketTot, 0, (size_t)(KMAX + 1) * 4, stream);
    pmap_kernel<<<(N + BS - 1) / BS, BS, 0, stream>>>(batch, pmap, N);
    bucket_hist_kernel<<<256, BS, 0, stream>>>(ei, bucketTot, E, K);
    bucket_scan_kernel<<<1, KMAX, 0, stream>>>(bucketTot, bucketStart, bucketCursor, K, (int)E, rowptr, N);
    partition_kernel<<<partBlocks, BS, 0, stream>>>(ei, bucketCursor, pairs, E, K);
    build_csr_kernel<<<K, RANGE, 0, stream>>>(pairs, bucketStart, rowptr, dinv, csr_src, N);

    // ---- layer 1 transform ----
    gemm_in_kernel<<<ginBlocks, BS, 0, stream>>>(x, W1, dinv, tpA, N);

    // ---- fused layers ----
    gather_fused_kernel<<<rowBlocks, BS, 0, stream>>>(rowptr, csr_src, tpA, dinv, b1, pmap,
                                                      pooled, 0, W2, tpB, N);
    gather_fused_kernel<<<rowBlocks, BS, 0, stream>>>(rowptr, csr_src, tpB, dinv, b2, pmap,
                                                      pooled, LAT, W3, tpA, N);
    gather_fused_kernel<<<rowBlocks, BS, 0, stream>>>(rowptr, csr_src, tpA, dinv, b3, pmap,
                                                      pooled, 2 * LAT, (const float*)nullptr,
                                                      (u16*)nullptr, N);

    // ---- MLP head ----
    mlp_head_kernel<<<G, HID, 0, stream>>>(pooled, Wl1, bl1, Wl2, bl2, out, G);
}